// Round 17
// baseline (305.022 us; speedup 1.0000x reference)
//
#include <hip/hip_runtime.h>
#include <cstdint>
#include <cstddef>

#define N 16384
#define NWORDS 256      // N/64 mask words per row
#define HID 16
#define F_IN 64
#define F_OUT 32
#define RCHUNK 8
#define RPC (N / RCHUNK)     // 2048 rows per spmm chunk
#define SPCH 64              // s partials (one per bx)
#define CB 4096              // pass-1 columns per block (16KB chunks)
#define NXB (N / CB)         // 4 x-blocks
#define RY 64                // pass-1 y-blocks
#define ROWCHUNK (N / RY)    // 256 rows per pass-1 block (32 per wave, 8 waves)
#define NPART RY             // 64 deg partials (block-reduced)

// permuted column mapping: word p, bit b  ->  column (p>>2)*256 + 4*b + (p&3)
__device__ __forceinline__ int perm_col(int p, int b) {
  return ((p >> 2) << 8) + (b << 2) + (p & 3);
}

// 64x64 bit-matrix transpose across a wave: in lane r = row r's word.
// out lane l bit b = in lane b bit l. 6 shfl_xor steps.
__device__ __forceinline__ unsigned long long bit_transpose64(unsigned long long x,
                                                              int lane) {
  const unsigned long long M[6] = {
    0x5555555555555555ULL, 0x3333333333333333ULL, 0x0F0F0F0F0F0F0F0FULL,
    0x00FF00FF00FF00FFULL, 0x0000FFFF0000FFFFULL, 0x00000000FFFFFFFFULL
  };
#pragma unroll
  for (int t = 0; t < 6; ++t) {
    int s = 1 << t;
    unsigned long long m = M[t];
    unsigned long long y = __shfl_xor(x, s, 64);
    x = (lane & s) ? ((x & ~m) | ((y & ~m) >> s))
                   : ((x & m) | ((y & m) << s));
  }
  return x;
}

// ---------- pass 1: column-block streaming, 16KB/row-visit (r16, ~200us) ----------
__global__ __launch_bounds__(512, 2)
void k_mask_deg(const float* __restrict__ A,
                unsigned long long* __restrict__ maskT,
                unsigned int* __restrict__ deg_part) {
  int wave = threadIdx.x >> 6, lane = threadIdx.x & 63;
  int jb = blockIdx.x * CB;
  int p0 = blockIdx.x * 64;
  int r0 = blockIdx.y * ROWCHUNK + wave * 32;
  const float4* A4 = (const float4*)A;
  size_t colbase = (size_t)(jb >> 2) + lane;
  unsigned int cnt[16][4];
#pragma unroll
  for (int k = 0; k < 16; ++k)
#pragma unroll
    for (int q = 0; q < 4; ++q) cnt[k][q] = 0u;
  __shared__ unsigned long long st[8][64][32];   // [wave][word][row] = 128 KB

#pragma unroll 1
  for (int g = 0; g < 32; ++g) {
    float4 v[16];
#pragma unroll
    for (int k = 0; k < 16; ++k)
      v[k] = A4[(size_t)(r0 + g) * (N / 4) + colbase + k * 64];
#pragma unroll
    for (int k = 0; k < 16; ++k) {
      bool n0 = (v[k].x != 0.f), n1 = (v[k].y != 0.f);
      bool n2 = (v[k].z != 0.f), n3 = (v[k].w != 0.f);
      unsigned long long b0 = __ballot(n0);
      unsigned long long b1 = __ballot(n1);
      unsigned long long b2 = __ballot(n2);
      unsigned long long b3 = __ballot(n3);
      cnt[k][0] += n0 ? 1u : 0u;  cnt[k][1] += n1 ? 1u : 0u;
      cnt[k][2] += n2 ? 1u : 0u;  cnt[k][3] += n3 ? 1u : 0u;
      if (lane < 4) {
        unsigned long long bq = (lane == 0) ? b0 : (lane == 1) ? b1
                              : (lane == 2) ? b2 : b3;
        st[wave][k * 4 + lane][g] = bq;
      }
    }
  }
  // flush 64 words x 32 rows: 2 words per iteration, all 64 lanes active
#pragma unroll 1
  for (int w2 = 0; w2 < 64; w2 += 2) {
    int w = w2 + (lane >> 5);
    int r = lane & 31;
    maskT[(size_t)(p0 + w) * N + r0 + r] = st[wave][w][r];
  }

  // block-reduce degree counts: reuse st as uint scratch
  __syncthreads();
  unsigned int* sred = (unsigned int*)&st[0][0][0];
#pragma unroll
  for (int k = 0; k < 16; ++k) {
    uint4 c4; c4.x = cnt[k][0]; c4.y = cnt[k][1]; c4.z = cnt[k][2]; c4.w = cnt[k][3];
    *(uint4*)(sred + wave * CB + k * 256 + 4 * lane) = c4;   // col = k*256+4*lane+q
  }
  __syncthreads();
  for (int c = threadIdx.x; c < CB; c += 512) {
    unsigned int sum = 0;
#pragma unroll
    for (int w8 = 0; w8 < 8; ++w8) sum += sred[w8 * CB + c];
    deg_part[(size_t)blockIdx.y * N + jb + c] = sum;
  }
}

// ---------- fused: deg reduce + dinv + z = x@W1 + wz; 4-wave channel-split ----------
__global__ void k_dinvz(const unsigned int* __restrict__ deg_part, int nparts,
                        const float* __restrict__ x, const float* __restrict__ W1,
                        float* __restrict__ dinv, float* __restrict__ z,
                        float* __restrict__ wz, unsigned int* __restrict__ done) {
  if (blockIdx.x == 0 && threadIdx.x == 0) *done = 0u;   // reset ticket each call
  __shared__ unsigned int sd[4][64];
  int lane = threadIdx.x & 63, wv = threadIdx.x >> 6;
  int i = blockIdx.x * 64 + lane;
  unsigned int dsum = 0;
#pragma unroll
  for (int w = 0; w < NPART / 4; ++w)
    dsum += deg_part[(size_t)(wv * (NPART / 4) + w) * N + i];
  sd[wv][lane] = dsum;
  __syncthreads();
  unsigned int tot = sd[0][lane] + sd[1][lane] + sd[2][lane] + sd[3][lane];
  float d = rsqrtf((float)(tot + 1u));         // +1 self-loop
  if (wv == 0) dinv[i] = d;
  int c0 = wv * 4;
  float zz[4];
#pragma unroll
  for (int cc = 0; cc < 4; ++cc) zz[cc] = 0.f;
  const float4* xr = (const float4*)(x + (size_t)i * F_IN);
#pragma unroll
  for (int k4 = 0; k4 < 16; ++k4) {
    float4 v = xr[k4];
#pragma unroll
    for (int cc = 0; cc < 4; ++cc) {
      zz[cc] += v.x * W1[(4 * k4 + 0) * HID + c0 + cc];
      zz[cc] += v.y * W1[(4 * k4 + 1) * HID + c0 + cc];
      zz[cc] += v.z * W1[(4 * k4 + 2) * HID + c0 + cc];
      zz[cc] += v.w * W1[(4 * k4 + 3) * HID + c0 + cc];
    }
  }
  float4 a; a.x = zz[0]; a.y = zz[1]; a.z = zz[2]; a.w = zz[3];
  ((float4*)(z + (size_t)i * HID))[wv] = a;
  float4 b; b.x = a.x * d; b.y = a.y * d; b.z = a.z * d; b.w = a.w * d;
  ((float4*)(wz + (size_t)i * HID))[wv] = b;
}

// ---------- mid: spmm with FUSED rowsum (single mask read) ----------
// 512 blocks: bx = bid&63 (word group), by = bid>>6 (row chunk of 2048).
// Per batch of 64 rows: lane's pre-transpose word = row's bits over cols
// 64p..64p+63 -> s contribution (walk, E[0.26] bits); cross-wave LDS sum ->
// s_part[bx][row]. Then transpose -> per-lane own-column walk -> acc (spmm).
__global__ void k_mid(const unsigned long long* __restrict__ maskT,
                      const float* __restrict__ dinv,
                      const float* __restrict__ wz,
                      float* __restrict__ s_part,
                      float* __restrict__ t_part) {
  int tid = threadIdx.x, bid = blockIdx.x;
  int lane = tid & 63, wv = tid >> 6;
  int bx = bid & 63, by = bid >> 6;
  int p = bx * 4 + wv;
  int i0 = by * RPC;
  const unsigned long long* mcol = maskT + (size_t)p * N + i0;
  __shared__ float s_lds[4][64];
  float acc[16];
#pragma unroll
  for (int c = 0; c < 16; ++c) acc[c] = 0.f;
  unsigned long long wvw = mcol[lane];
#pragma unroll 1
  for (int batch = 0; batch < RPC / 64; ++batch) {
    unsigned long long wnext = (batch + 1 < RPC / 64)
                             ? mcol[(batch + 1) * 64 + lane] : 0ull;
    int ib = i0 + batch * 64;
    // rowsum contribution: lane owns row ib+lane (pre-transpose word)
    float sw = 0.f;
    unsigned long long w0 = wvw;
    while (w0) {
      int b = __builtin_ctzll(w0);
      w0 &= w0 - 1;
      sw += dinv[perm_col(p, b)];
    }
    s_lds[wv][lane] = sw;
    // spmm: transpose -> lane's word holds its OWN column's 64 row-bits
    unsigned long long x = bit_transpose64(wvw, lane);
    while (x) {
      int b = __builtin_ctzll(x);
      x &= x - 1;
      const float4* wr = (const float4*)(wz + (size_t)(ib + b) * HID);
#pragma unroll
      for (int q = 0; q < 4; ++q) {
        float4 v = wr[q];
        acc[q * 4 + 0] += v.x; acc[q * 4 + 1] += v.y;
        acc[q * 4 + 2] += v.z; acc[q * 4 + 3] += v.w;
      }
    }
    __syncthreads();
    if (wv == 0) {
      float tot = s_lds[0][lane] + s_lds[1][lane] + s_lds[2][lane] + s_lds[3][lane];
      s_part[(size_t)bx * N + ib + lane] = tot;
    }
    __syncthreads();
    wvw = wnext;
  }
  int t = bx * 256 + tid;                      // = p*64 + lane
  float4* tp = (float4*)t_part;
#pragma unroll
  for (int q = 0; q < 4; ++q) {
    float4 v = make_float4(acc[q * 4 + 0], acc[q * 4 + 1],
                           acc[q * 4 + 2], acc[q * 4 + 3]);
    tp[((size_t)by * 4 + q) * N + t] = v;      // coalesced
  }
}

// ---------- combine + fused final (last-block-done) ----------
__global__ void k_combine(const float* __restrict__ t_part,
                          const float* __restrict__ z,
                          const float* __restrict__ dinv,
                          const float* __restrict__ sp,
                          const float* __restrict__ b1,
                          const float* __restrict__ W2,
                          const float* __restrict__ b2,
                          float* __restrict__ u_part,
                          unsigned int* __restrict__ done,
                          float* __restrict__ out) {
  int tid = threadIdx.x;
  int t = blockIdx.x * 64 + tid;
  int col = perm_col(t >> 6, t & 63);
  const float4* tp = (const float4*)t_part;
  float acc[16];
#pragma unroll
  for (int c = 0; c < 16; ++c) acc[c] = 0.f;
#pragma unroll
  for (int ch = 0; ch < RCHUNK; ++ch) {
#pragma unroll
    for (int q = 0; q < 4; ++q) {
      float4 v = tp[((size_t)ch * 4 + q) * N + t];
      acc[q * 4 + 0] += v.x; acc[q * 4 + 1] += v.y;
      acc[q * 4 + 2] += v.z; acc[q * 4 + 3] += v.w;
    }
  }
  float zz[16];
  const float4* zr = (const float4*)(z + (size_t)col * HID);
#pragma unroll
  for (int q = 0; q < 4; ++q) {
    float4 v = zr[q];
    zz[q * 4 + 0] = v.x; zz[q * 4 + 1] = v.y; zz[q * 4 + 2] = v.z; zz[q * 4 + 3] = v.w;
  }
  float sv = 0.f;
#pragma unroll 8
  for (int sc = 0; sc < SPCH; ++sc) sv += sp[(size_t)sc * N + col];
  float d = dinv[col];
  float rj = d * (d + sv);
  float uc[16];
#pragma unroll
  for (int c = 0; c < 16; ++c) {
    float pre = d * (d * zz[c] + acc[c]) + b1[c];
    float h = pre > 0.f ? pre : 0.f;
    uc[c] = rj * h;
  }
#pragma unroll
  for (int c = 0; c < 16; ++c) {
#pragma unroll
    for (int off = 32; off > 0; off >>= 1) uc[c] += __shfl_down(uc[c], off);
  }
  if (tid == 0) {
#pragma unroll
    for (int c = 0; c < 16; ++c) u_part[blockIdx.x * 16 + c] = uc[c];
  }

  // ---- last-block final ----
  __shared__ int isLast;
  if (tid == 0) {
    __threadfence();                            // flush u_part to device scope
    unsigned int ticket = atomicAdd(done, 1u);
    isLast = (ticket == gridDim.x - 1) ? 1 : 0;
  }
  __syncthreads();
  if (isLast) {
    __threadfence();                            // acquire others' u_part
    __shared__ float red2[4][17];
    __shared__ float uu[16];
    int c = tid & 15, g = tid >> 4;             // 64 threads: 4 groups x 16
    float a = 0.f;
#pragma unroll 1
    for (int b = g; b < 256; b += 4) a += u_part[(size_t)b * 16 + c];
    red2[g][c] = a;
    __syncthreads();
    if (tid < 16) uu[tid] = red2[0][tid] + red2[1][tid] + red2[2][tid] + red2[3][tid];
    __syncthreads();
    if (tid < 32) {
      float o = (float)N * b2[tid];
#pragma unroll
      for (int c2 = 0; c2 < 16; ++c2) o += uu[c2] * W2[c2 * F_OUT + tid];
      out[tid] = o;
    }
  }
}

// ---------- fallback path (no workspace): direct-A kernels ----------
__global__ void k_deg_only(const float* __restrict__ A,
                           unsigned int* __restrict__ deg) {
  int j = blockIdx.x * 256 + threadIdx.x;
  int i0 = blockIdx.y * 512;
  unsigned int cnt = 0;
#pragma unroll 4
  for (int i = i0; i < i0 + 512; ++i) {
    float a = A[(size_t)i * N + j];
    cnt += (a != 0.f) ? 1u : 0u;
  }
  atomicAdd(&deg[j], cnt);
}

__global__ void k_rowsum_direct(const float* __restrict__ A,
                                const float* __restrict__ dinv,
                                float* __restrict__ s) {
  int wave = threadIdx.x >> 6, lane = threadIdx.x & 63;
  int i = blockIdx.x * 4 + wave;
  const float* Ar = A + (size_t)i * N;
  float acc = 0.f;
  for (int t = 0; t < N; t += 64) {
    float a = Ar[t + lane];
    if (a != 0.f) acc += dinv[t + lane];
  }
#pragma unroll
  for (int off = 32; off > 0; off >>= 1) acc += __shfl_down(acc, off);
  if (lane == 0) s[i] = acc;
}

__global__ void k_spmm_direct(const float* __restrict__ A,
                              const float* __restrict__ wz,
                              float* __restrict__ t_part) {
  int j = blockIdx.x * 256 + threadIdx.x;
  int i0 = blockIdx.y * RPC;
  float acc[16];
#pragma unroll
  for (int c = 0; c < 16; ++c) acc[c] = 0.f;
  for (int i = i0; i < i0 + RPC; ++i) {
    float a = A[(size_t)i * N + j];
    if (a != 0.f) {
      const float4* wr = (const float4*)(wz + (size_t)i * HID);
#pragma unroll
      for (int q = 0; q < 4; ++q) {
        float4 v = wr[q];
        acc[q * 4 + 0] += v.x; acc[q * 4 + 1] += v.y;
        acc[q * 4 + 2] += v.z; acc[q * 4 + 3] += v.w;
      }
    }
  }
  float4* tp = (float4*)t_part;
#pragma unroll
  for (int q = 0; q < 4; ++q) {
    float4 v = make_float4(acc[q * 4 + 0], acc[q * 4 + 1],
                           acc[q * 4 + 2], acc[q * 4 + 3]);
    tp[((size_t)blockIdx.y * 4 + q) * N + j] = v;
  }
}

__global__ void k_combine_fb(const float* __restrict__ t_part,
                             const float* __restrict__ z,
                             const float* __restrict__ dinv,
                             const float* __restrict__ sp,
                             const float* __restrict__ b1,
                             float* __restrict__ u_part) {
  int j = blockIdx.x * 64 + threadIdx.x;
  int lane = threadIdx.x & 63;
  const float4* tp = (const float4*)t_part;
  float acc[16];
#pragma unroll
  for (int c = 0; c < 16; ++c) acc[c] = 0.f;
#pragma unroll
  for (int ch = 0; ch < RCHUNK; ++ch) {
#pragma unroll
    for (int q = 0; q < 4; ++q) {
      float4 v = tp[((size_t)ch * 4 + q) * N + j];
      acc[q * 4 + 0] += v.x; acc[q * 4 + 1] += v.y;
      acc[q * 4 + 2] += v.z; acc[q * 4 + 3] += v.w;
    }
  }
  float zz[16];
  const float4* zr = (const float4*)(z + (size_t)j * HID);
#pragma unroll
  for (int q = 0; q < 4; ++q) {
    float4 v = zr[q];
    zz[q * 4 + 0] = v.x; zz[q * 4 + 1] = v.y; zz[q * 4 + 2] = v.z; zz[q * 4 + 3] = v.w;
  }
  float sv = sp[j];
  float d = dinv[j];
  float rj = d * (d + sv);
  float uc[16];
#pragma unroll
  for (int c = 0; c < 16; ++c) {
    float pre = d * (d * zz[c] + acc[c]) + b1[c];
    float h = pre > 0.f ? pre : 0.f;
    uc[c] = rj * h;
  }
#pragma unroll
  for (int c = 0; c < 16; ++c) {
#pragma unroll
    for (int off = 32; off > 0; off >>= 1) uc[c] += __shfl_down(uc[c], off);
  }
  if (lane == 0) {
#pragma unroll
    for (int c = 0; c < 16; ++c) u_part[blockIdx.x * 16 + c] = uc[c];
  }
}

__global__ void k_final_fb(const float* __restrict__ u_part,
                           const float* __restrict__ W2,
                           const float* __restrict__ b2,
                           float* __restrict__ out) {
  __shared__ float red[16][17];
  __shared__ float u[16];
  int t = threadIdx.x;
  int c = t & 15, g = t >> 4;
  float a = 0.f;
#pragma unroll
  for (int b = 0; b < 16; ++b) a += u_part[(size_t)(g * 16 + b) * 16 + c];
  red[g][c] = a;
  __syncthreads();
  if (t < 16) {
    float s = 0.f;
#pragma unroll
    for (int g2 = 0; g2 < 16; ++g2) s += red[g2][t];
    u[t] = s;
  }
  __syncthreads();
  if (t < 32) {
    float o = (float)N * b2[t];
#pragma unroll
    for (int c2 = 0; c2 < 16; ++c2) o += u[c2] * W2[c2 * F_OUT + t];
    out[t] = o;
  }
}

// fallback dinvz (reads single deg array)
__global__ void k_dinvz_fb(const unsigned int* __restrict__ deg,
                           const float* __restrict__ x, const float* __restrict__ W1,
                           float* __restrict__ dinv, float* __restrict__ z,
                           float* __restrict__ wz) {
  int i = blockIdx.x * 64 + threadIdx.x;
  float d = rsqrtf((float)(deg[i] + 1u));
  dinv[i] = d;
  float zz[16];
#pragma unroll
  for (int c = 0; c < 16; ++c) zz[c] = 0.f;
  const float4* xr = (const float4*)(x + (size_t)i * F_IN);
#pragma unroll
  for (int k4 = 0; k4 < 16; ++k4) {
    float4 v = xr[k4];
#pragma unroll
    for (int c = 0; c < 16; ++c) {
      zz[c] += v.x * W1[(4 * k4 + 0) * HID + c];
      zz[c] += v.y * W1[(4 * k4 + 1) * HID + c];
      zz[c] += v.z * W1[(4 * k4 + 2) * HID + c];
      zz[c] += v.w * W1[(4 * k4 + 3) * HID + c];
    }
  }
  float4* z4 = (float4*)(z + (size_t)i * HID);
  float4* w4 = (float4*)(wz + (size_t)i * HID);
#pragma unroll
  for (int q = 0; q < 4; ++q) {
    float4 a; a.x = zz[4*q]; a.y = zz[4*q+1]; a.z = zz[4*q+2]; a.w = zz[4*q+3];
    z4[q] = a;
    float4 b; b.x = a.x * d; b.y = a.y * d; b.z = a.z * d; b.w = a.w * d;
    w4[q] = b;
  }
}

extern "C" void kernel_launch(void* const* d_in, const int* in_sizes, int n_in,
                              void* d_out, int out_size, void* d_ws, size_t ws_size,
                              hipStream_t stream) {
  const float* A  = (const float*)d_in[0];
  const float* x  = (const float*)d_in[1];
  const float* W1 = (const float*)d_in[2];
  const float* b1 = (const float*)d_in[3];
  const float* W2 = (const float*)d_in[4];
  const float* b2 = (const float*)d_in[5];
  float* out = (float*)d_out;

  char* ws = (char*)d_ws;
  size_t off = 0;
  auto alloc = [&](size_t bytes) {
    char* p = ws + off;
    off += (bytes + 255) & ~(size_t)255;
    return p;
  };

  unsigned int* deg_part = (unsigned int*)alloc((size_t)NPART * N * 4);
  float* dinv       = (float*)alloc((size_t)N * 4);
  float* s_part     = (float*)alloc((size_t)SPCH * N * 4);
  float* z          = (float*)alloc((size_t)N * HID * 4);
  float* wz         = (float*)alloc((size_t)N * HID * 4);
  float* u_part     = (float*)alloc(256 * 16 * 4);
  unsigned int* done = (unsigned int*)alloc(256);
  float* t_part     = (float*)alloc((size_t)RCHUNK * N * HID * 4);
  unsigned long long* maskT = (unsigned long long*)alloc((size_t)N * NWORDS * 8);
  bool use_mask = (ws_size >= off);   // ~54 MB needed for the mask path

  if (use_mask) {
    k_mask_deg<<<dim3(NXB, RY), 512, 0, stream>>>(A, maskT, deg_part);
    k_dinvz<<<N / 64, 256, 0, stream>>>(deg_part, NPART, x, W1, dinv, z, wz, done);
    k_mid<<<512, 256, 0, stream>>>(maskT, dinv, wz, s_part, t_part);
    k_combine<<<256, 64, 0, stream>>>(t_part, z, dinv, s_part, b1, W2, b2,
                                      u_part, done, out);
  } else {
    hipMemsetAsync(deg_part, 0, (size_t)N * 4, stream);
    k_deg_only<<<dim3(64, 32), 256, 0, stream>>>(A, deg_part);
    k_dinvz_fb<<<N / 64, 64, 0, stream>>>(deg_part, x, W1, dinv, z, wz);
    k_rowsum_direct<<<N / 4, 256, 0, stream>>>(A, dinv, s_part);
    k_spmm_direct<<<dim3(64, RCHUNK), 256, 0, stream>>>(A, wz, t_part);
    k_combine_fb<<<N / 64, 64, 0, stream>>>(t_part, z, dinv, s_part, b1, u_part);
    k_final_fb<<<1, 256, 0, stream>>>(u_part, W2, b2, out);
  }
}

// Round 18
// 269.046 us; speedup vs baseline: 1.1337x; 1.1337x over previous
//
#include <hip/hip_runtime.h>
#include <cstdint>
#include <cstddef>

#define N 16384
#define NWORDS 256      // N/64 mask words per row
#define HID 16
#define F_IN 64
#define F_OUT 32
#define RCHUNK 16
#define RPC (N / RCHUNK)     // 1024 rows per spmm chunk
#define PCH 8                // p-chunks for rowsum partials
#define PW (NWORDS / PCH)    // 32 p-words per chunk
#define CB 4096              // pass-1 columns per block (16KB chunks)
#define NXB (N / CB)         // 4 x-blocks
#define RY 64                // pass-1 y-blocks
#define ROWCHUNK (N / RY)    // 256 rows per pass-1 block (32 per wave, 8 waves)
#define NPART RY             // 64 deg partials (block-reduced)

// permuted column mapping: word p, bit b  ->  column (p>>2)*256 + 4*b + (p&3)
__device__ __forceinline__ int perm_col(int p, int b) {
  return ((p >> 2) << 8) + (b << 2) + (p & 3);
}

__device__ __forceinline__ unsigned long long readlane64(unsigned long long v, int l) {
  union { unsigned long long u; unsigned int s[2]; } x;
  x.u = v;
  unsigned int lo = __builtin_amdgcn_readlane(x.s[0], l);
  unsigned int hi = __builtin_amdgcn_readlane(x.s[1], l);
  return ((unsigned long long)hi << 32) | lo;
}

// 64x64 bit-matrix transpose across a wave: in lane r = row r's word.
// out lane l bit b = in lane b bit l. 6 shfl_xor steps.
__device__ __forceinline__ unsigned long long bit_transpose64(unsigned long long x,
                                                              int lane) {
  const unsigned long long M[6] = {
    0x5555555555555555ULL, 0x3333333333333333ULL, 0x0F0F0F0F0F0F0F0FULL,
    0x00FF00FF00FF00FFULL, 0x0000FFFF0000FFFFULL, 0x00000000FFFFFFFFULL
  };
#pragma unroll
  for (int t = 0; t < 6; ++t) {
    int s = 1 << t;
    unsigned long long m = M[t];
    unsigned long long y = __shfl_xor(x, s, 64);
    x = (lane & s) ? ((x & ~m) | ((y & ~m) >> s))
                   : ((x & m) | ((y & m) << s));
  }
  return x;
}

// ---------- pass 1: column-block streaming, 16KB/row-visit ----------
// Block: CB=4096 cols x 256 rows, 512 threads (8 waves); wave owns 32 rows,
// reads one FULL 16KB row-segment per 16-load batch (contiguous). Ballots ->
// LDS stage (128KB) -> coalesced column-major flush (2 words/iter, all 64
// lanes). Degrees in registers -> LDS block-reduce -> one partial per block.
// Word p = bx*64 + k*4 + q holds cols jb + k*256 + 4*bit + q  (= perm_col).
__global__ __launch_bounds__(512, 2)
void k_mask_deg(const float* __restrict__ A,
                unsigned long long* __restrict__ maskT,
                unsigned int* __restrict__ deg_part) {
  int wave = threadIdx.x >> 6, lane = threadIdx.x & 63;
  int jb = blockIdx.x * CB;
  int p0 = blockIdx.x * 64;
  int r0 = blockIdx.y * ROWCHUNK + wave * 32;
  const float4* A4 = (const float4*)A;
  size_t colbase = (size_t)(jb >> 2) + lane;
  unsigned int cnt[16][4];
#pragma unroll
  for (int k = 0; k < 16; ++k)
#pragma unroll
    for (int q = 0; q < 4; ++q) cnt[k][q] = 0u;
  __shared__ unsigned long long st[8][64][32];   // [wave][word][row] = 128 KB

#pragma unroll 1
  for (int g = 0; g < 32; ++g) {
    float4 v[16];
#pragma unroll
    for (int k = 0; k < 16; ++k)
      v[k] = A4[(size_t)(r0 + g) * (N / 4) + colbase + k * 64];
#pragma unroll
    for (int k = 0; k < 16; ++k) {
      bool n0 = (v[k].x != 0.f), n1 = (v[k].y != 0.f);
      bool n2 = (v[k].z != 0.f), n3 = (v[k].w != 0.f);
      unsigned long long b0 = __ballot(n0);
      unsigned long long b1 = __ballot(n1);
      unsigned long long b2 = __ballot(n2);
      unsigned long long b3 = __ballot(n3);
      cnt[k][0] += n0 ? 1u : 0u;  cnt[k][1] += n1 ? 1u : 0u;
      cnt[k][2] += n2 ? 1u : 0u;  cnt[k][3] += n3 ? 1u : 0u;
      if (lane < 4) {
        unsigned long long bq = (lane == 0) ? b0 : (lane == 1) ? b1
                              : (lane == 2) ? b2 : b3;
        st[wave][k * 4 + lane][g] = bq;
      }
    }
  }
  // flush 64 words x 32 rows: 2 words per iteration, all 64 lanes active
#pragma unroll 1
  for (int w2 = 0; w2 < 64; w2 += 2) {
    int w = w2 + (lane >> 5);
    int r = lane & 31;
    maskT[(size_t)(p0 + w) * N + r0 + r] = st[wave][w][r];
  }

  // block-reduce degree counts: reuse st as uint scratch (128 KB)
  __syncthreads();
  unsigned int* sred = (unsigned int*)&st[0][0][0];
#pragma unroll
  for (int k = 0; k < 16; ++k) {
    uint4 c4; c4.x = cnt[k][0]; c4.y = cnt[k][1]; c4.z = cnt[k][2]; c4.w = cnt[k][3];
    *(uint4*)(sred + wave * CB + k * 256 + 4 * lane) = c4;   // col = k*256+4*lane+q
  }
  __syncthreads();
  for (int c = threadIdx.x; c < CB; c += 512) {
    unsigned int sum = 0;
#pragma unroll
    for (int w8 = 0; w8 < 8; ++w8) sum += sred[w8 * CB + c];
    deg_part[(size_t)blockIdx.y * N + jb + c] = sum;
  }
}

// ---------- fused: deg reduce + dinv + z = x@W1 + wz; 4-wave channel-split ----------
__global__ void k_dinvz(const unsigned int* __restrict__ deg_part, int nparts,
                        const float* __restrict__ x, const float* __restrict__ W1,
                        float* __restrict__ dinv, float* __restrict__ z,
                        float* __restrict__ wz, unsigned int* __restrict__ done) {
  if (blockIdx.x == 0 && threadIdx.x == 0) *done = 0u;   // reset ticket each call
  __shared__ unsigned int sd[4][64];
  int lane = threadIdx.x & 63, wv = threadIdx.x >> 6;
  int i = blockIdx.x * 64 + lane;
  // deg partials split 16 per wave, LDS-reduced (deterministic)
  unsigned int dsum = 0;
#pragma unroll
  for (int w = 0; w < NPART / 4; ++w)
    dsum += deg_part[(size_t)(wv * (NPART / 4) + w) * N + i];
  sd[wv][lane] = dsum;
  __syncthreads();
  unsigned int tot = sd[0][lane] + sd[1][lane] + sd[2][lane] + sd[3][lane];
  float d = rsqrtf((float)(tot + 1u));         // +1 self-loop
  if (wv == 0) dinv[i] = d;
  // wave wv computes channels 4wv..4wv+3
  int c0 = wv * 4;
  float zz[4];
#pragma unroll
  for (int cc = 0; cc < 4; ++cc) zz[cc] = 0.f;
  const float4* xr = (const float4*)(x + (size_t)i * F_IN);
#pragma unroll
  for (int k4 = 0; k4 < 16; ++k4) {
    float4 v = xr[k4];
#pragma unroll
    for (int cc = 0; cc < 4; ++cc) {
      zz[cc] += v.x * W1[(4 * k4 + 0) * HID + c0 + cc];
      zz[cc] += v.y * W1[(4 * k4 + 1) * HID + c0 + cc];
      zz[cc] += v.z * W1[(4 * k4 + 2) * HID + c0 + cc];
      zz[cc] += v.w * W1[(4 * k4 + 3) * HID + c0 + cc];
    }
  }
  float4 a; a.x = zz[0]; a.y = zz[1]; a.z = zz[2]; a.w = zz[3];
  ((float4*)(z + (size_t)i * HID))[wv] = a;
  float4 b; b.x = a.x * d; b.y = a.y * d; b.z = a.z * d; b.w = a.w * d;
  ((float4*)(wz + (size_t)i * HID))[wv] = b;
}

// ---------- merged mid: spmm units (0..1023, transpose walk) + rowsum ----------
__global__ void k_mid(const unsigned long long* __restrict__ maskT,
                      const float* __restrict__ dinv,
                      const float* __restrict__ wz,
                      float* __restrict__ s_part,
                      float* __restrict__ t_part) {
  int tid = threadIdx.x, bid = blockIdx.x;
  int lane = tid & 63, wv = tid >> 6;
  if (bid < 1024) {
    // ---- spmm unit: per-lane column walk via 64x64 bit transpose ----
    int bx = bid & 63, by = bid >> 6;
    int p = bx * 4 + wv;
    int i0 = by * RPC;
    const unsigned long long* mcol = maskT + (size_t)p * N + i0;
    float acc[16];
#pragma unroll
    for (int c = 0; c < 16; ++c) acc[c] = 0.f;
    unsigned long long wvw = mcol[lane];
#pragma unroll 1
    for (int batch = 0; batch < RPC / 64; ++batch) {
      unsigned long long wnext = (batch + 1 < RPC / 64)
                               ? mcol[(batch + 1) * 64 + lane] : 0ull;
      int ib = i0 + batch * 64;
      // lane's word now holds its OWN column's 64 row-bits
      unsigned long long x = bit_transpose64(wvw, lane);
      while (x) {
        int b = __builtin_ctzll(x);
        x &= x - 1;
        const float4* wr = (const float4*)(wz + (size_t)(ib + b) * HID);
#pragma unroll
        for (int q = 0; q < 4; ++q) {
          float4 v = wr[q];
          acc[q * 4 + 0] += v.x; acc[q * 4 + 1] += v.y;
          acc[q * 4 + 2] += v.z; acc[q * 4 + 3] += v.w;
        }
      }
      wvw = wnext;
    }
    int t = bx * 256 + tid;
    float4* tp = (float4*)t_part;
#pragma unroll
    for (int q = 0; q < 4; ++q) {
      float4 v = make_float4(acc[q * 4 + 0], acc[q * 4 + 1],
                             acc[q * 4 + 2], acc[q * 4 + 3]);
      tp[((size_t)by * 4 + q) * N + t] = v;
    }
  } else {
    // ---- rowsum unit ----
    int rb = bid - 1024;
    int rg = rb >> 1;
    int pc = (rb & 1) * 4 + wv;
    int row = rg * 64 + lane;
    int pbase = pc * PW;
    float acc = 0.f;
#pragma unroll 1
    for (int b = 0; b < PW / 8; ++b) {
      unsigned long long w[8];
#pragma unroll
      for (int u = 0; u < 8; ++u)
        w[u] = maskT[(size_t)(pbase + b * 8 + u) * N + row];
#pragma unroll
      for (int u = 0; u < 8; ++u) {
        int p = pbase + b * 8 + u;
        unsigned long long wd = w[u];
        while (wd) {
          int bb = __builtin_ctzll(wd);
          wd &= wd - 1;
          acc += dinv[perm_col(p, bb)];
        }
      }
    }
    s_part[(size_t)pc * N + row] = acc;
  }
}

// ---------- combine + fused final (last-block-done) ----------
__global__ void k_combine(const float* __restrict__ t_part,
                          const float* __restrict__ z,
                          const float* __restrict__ dinv,
                          const float* __restrict__ sp,
                          const float* __restrict__ b1,
                          const float* __restrict__ W2,
                          const float* __restrict__ b2,
                          float* __restrict__ u_part,
                          unsigned int* __restrict__ done,
                          float* __restrict__ out) {
  int tid = threadIdx.x;
  int t = blockIdx.x * 64 + tid;
  int col = perm_col(t >> 6, t & 63);
  const float4* tp = (const float4*)t_part;
  float acc[16];
#pragma unroll
  for (int c = 0; c < 16; ++c) acc[c] = 0.f;
#pragma unroll
  for (int ch = 0; ch < RCHUNK; ++ch) {
#pragma unroll
    for (int q = 0; q < 4; ++q) {
      float4 v = tp[((size_t)ch * 4 + q) * N + t];
      acc[q * 4 + 0] += v.x; acc[q * 4 + 1] += v.y;
      acc[q * 4 + 2] += v.z; acc[q * 4 + 3] += v.w;
    }
  }
  float zz[16];
  const float4* zr = (const float4*)(z + (size_t)col * HID);
#pragma unroll
  for (int q = 0; q < 4; ++q) {
    float4 v = zr[q];
    zz[q * 4 + 0] = v.x; zz[q * 4 + 1] = v.y; zz[q * 4 + 2] = v.z; zz[q * 4 + 3] = v.w;
  }
  float sv = 0.f;
#pragma unroll 8
  for (int sc = 0; sc < PCH; ++sc) sv += sp[(size_t)sc * N + col];
  float d = dinv[col];
  float rj = d * (d + sv);
  float uc[16];
#pragma unroll
  for (int c = 0; c < 16; ++c) {
    float pre = d * (d * zz[c] + acc[c]) + b1[c];
    float h = pre > 0.f ? pre : 0.f;
    uc[c] = rj * h;
  }
#pragma unroll
  for (int c = 0; c < 16; ++c) {
#pragma unroll
    for (int off = 32; off > 0; off >>= 1) uc[c] += __shfl_down(uc[c], off);
  }
  if (tid == 0) {
#pragma unroll
    for (int c = 0; c < 16; ++c) u_part[blockIdx.x * 16 + c] = uc[c];
  }

  // ---- last-block final ----
  __shared__ int isLast;
  if (tid == 0) {
    __threadfence();                            // flush u_part to device scope
    unsigned int ticket = atomicAdd(done, 1u);
    isLast = (ticket == gridDim.x - 1) ? 1 : 0;
  }
  __syncthreads();
  if (isLast) {
    __threadfence();                            // acquire others' u_part
    __shared__ float red2[4][17];
    __shared__ float uu[16];
    int c = tid & 15, g = tid >> 4;             // 64 threads: 4 groups x 16
    float a = 0.f;
#pragma unroll 1
    for (int b = g; b < 256; b += 4) a += u_part[(size_t)b * 16 + c];
    red2[g][c] = a;
    __syncthreads();
    if (tid < 16) uu[tid] = red2[0][tid] + red2[1][tid] + red2[2][tid] + red2[3][tid];
    __syncthreads();
    if (tid < 32) {
      float o = (float)N * b2[tid];
#pragma unroll
      for (int c2 = 0; c2 < 16; ++c2) o += uu[c2] * W2[c2 * F_OUT + tid];
      out[tid] = o;
    }
  }
}

// ---------- fallback path (no workspace): direct-A kernels ----------
__global__ void k_deg_only(const float* __restrict__ A,
                           unsigned int* __restrict__ deg) {
  int j = blockIdx.x * 256 + threadIdx.x;
  int i0 = blockIdx.y * 512;
  unsigned int cnt = 0;
#pragma unroll 4
  for (int i = i0; i < i0 + 512; ++i) {
    float a = A[(size_t)i * N + j];
    cnt += (a != 0.f) ? 1u : 0u;
  }
  atomicAdd(&deg[j], cnt);
}

__global__ void k_rowsum_direct(const float* __restrict__ A,
                                const float* __restrict__ dinv,
                                float* __restrict__ s) {
  int wave = threadIdx.x >> 6, lane = threadIdx.x & 63;
  int i = blockIdx.x * 4 + wave;
  const float* Ar = A + (size_t)i * N;
  float acc = 0.f;
  for (int t = 0; t < N; t += 64) {
    float a = Ar[t + lane];
    if (a != 0.f) acc += dinv[t + lane];
  }
#pragma unroll
  for (int off = 32; off > 0; off >>= 1) acc += __shfl_down(acc, off);
  if (lane == 0) s[i] = acc;
}

__global__ void k_spmm_direct(const float* __restrict__ A,
                              const float* __restrict__ wz,
                              float* __restrict__ t_part) {
  int j = blockIdx.x * 256 + threadIdx.x;
  int i0 = blockIdx.y * RPC;
  float acc[16];
#pragma unroll
  for (int c = 0; c < 16; ++c) acc[c] = 0.f;
  for (int i = i0; i < i0 + RPC; ++i) {
    float a = A[(size_t)i * N + j];
    if (a != 0.f) {
      const float4* wr = (const float4*)(wz + (size_t)i * HID);
#pragma unroll
      for (int q = 0; q < 4; ++q) {
        float4 v = wr[q];
        acc[q * 4 + 0] += v.x; acc[q * 4 + 1] += v.y;
        acc[q * 4 + 2] += v.z; acc[q * 4 + 3] += v.w;
      }
    }
  }
  float4* tp = (float4*)t_part;
#pragma unroll
  for (int q = 0; q < 4; ++q) {
    float4 v = make_float4(acc[q * 4 + 0], acc[q * 4 + 1],
                           acc[q * 4 + 2], acc[q * 4 + 3]);
    tp[((size_t)blockIdx.y * 4 + q) * N + j] = v;
  }
}

__global__ void k_combine_fb(const float* __restrict__ t_part,
                             const float* __restrict__ z,
                             const float* __restrict__ dinv,
                             const float* __restrict__ sp,
                             const float* __restrict__ b1,
                             float* __restrict__ u_part) {
  int j = blockIdx.x * 64 + threadIdx.x;
  int lane = threadIdx.x & 63;
  const float4* tp = (const float4*)t_part;
  float acc[16];
#pragma unroll
  for (int c = 0; c < 16; ++c) acc[c] = 0.f;
#pragma unroll
  for (int ch = 0; ch < RCHUNK; ++ch) {
#pragma unroll
    for (int q = 0; q < 4; ++q) {
      float4 v = tp[((size_t)ch * 4 + q) * N + j];
      acc[q * 4 + 0] += v.x; acc[q * 4 + 1] += v.y;
      acc[q * 4 + 2] += v.z; acc[q * 4 + 3] += v.w;
    }
  }
  float zz[16];
  const float4* zr = (const float4*)(z + (size_t)j * HID);
#pragma unroll
  for (int q = 0; q < 4; ++q) {
    float4 v = zr[q];
    zz[q * 4 + 0] = v.x; zz[q * 4 + 1] = v.y; zz[q * 4 + 2] = v.z; zz[q * 4 + 3] = v.w;
  }
  float sv = sp[j];
  float d = dinv[j];
  float rj = d * (d + sv);
  float uc[16];
#pragma unroll
  for (int c = 0; c < 16; ++c) {
    float pre = d * (d * zz[c] + acc[c]) + b1[c];
    float h = pre > 0.f ? pre : 0.f;
    uc[c] = rj * h;
  }
#pragma unroll
  for (int c = 0; c < 16; ++c) {
#pragma unroll
    for (int off = 32; off > 0; off >>= 1) uc[c] += __shfl_down(uc[c], off);
  }
  if (lane == 0) {
#pragma unroll
    for (int c = 0; c < 16; ++c) u_part[blockIdx.x * 16 + c] = uc[c];
  }
}

__global__ void k_final_fb(const float* __restrict__ u_part,
                           const float* __restrict__ W2,
                           const float* __restrict__ b2,
                           float* __restrict__ out) {
  __shared__ float red[16][17];
  __shared__ float u[16];
  int t = threadIdx.x;
  int c = t & 15, g = t >> 4;
  float a = 0.f;
#pragma unroll
  for (int b = 0; b < 16; ++b) a += u_part[(size_t)(g * 16 + b) * 16 + c];
  red[g][c] = a;
  __syncthreads();
  if (t < 16) {
    float s = 0.f;
#pragma unroll
    for (int g2 = 0; g2 < 16; ++g2) s += red[g2][t];
    u[t] = s;
  }
  __syncthreads();
  if (t < 32) {
    float o = (float)N * b2[t];
#pragma unroll
    for (int c2 = 0; c2 < 16; ++c2) o += u[c2] * W2[c2 * F_OUT + t];
    out[t] = o;
  }
}

// fallback dinvz (reads single deg array)
__global__ void k_dinvz_fb(const unsigned int* __restrict__ deg,
                           const float* __restrict__ x, const float* __restrict__ W1,
                           float* __restrict__ dinv, float* __restrict__ z,
                           float* __restrict__ wz) {
  int i = blockIdx.x * 64 + threadIdx.x;
  float d = rsqrtf((float)(deg[i] + 1u));
  dinv[i] = d;
  float zz[16];
#pragma unroll
  for (int c = 0; c < 16; ++c) zz[c] = 0.f;
  const float4* xr = (const float4*)(x + (size_t)i * F_IN);
#pragma unroll
  for (int k4 = 0; k4 < 16; ++k4) {
    float4 v = xr[k4];
#pragma unroll
    for (int c = 0; c < 16; ++c) {
      zz[c] += v.x * W1[(4 * k4 + 0) * HID + c];
      zz[c] += v.y * W1[(4 * k4 + 1) * HID + c];
      zz[c] += v.z * W1[(4 * k4 + 2) * HID + c];
      zz[c] += v.w * W1[(4 * k4 + 3) * HID + c];
    }
  }
  float4* z4 = (float4*)(z + (size_t)i * HID);
  float4* w4 = (float4*)(wz + (size_t)i * HID);
#pragma unroll
  for (int q = 0; q < 4; ++q) {
    float4 a; a.x = zz[4*q]; a.y = zz[4*q+1]; a.z = zz[4*q+2]; a.w = zz[4*q+3];
    z4[q] = a;
    float4 b; b.x = a.x * d; b.y = a.y * d; b.z = a.z * d; b.w = a.w * d;
    w4[q] = b;
  }
}

extern "C" void kernel_launch(void* const* d_in, const int* in_sizes, int n_in,
                              void* d_out, int out_size, void* d_ws, size_t ws_size,
                              hipStream_t stream) {
  const float* A  = (const float*)d_in[0];
  const float* x  = (const float*)d_in[1];
  const float* W1 = (const float*)d_in[2];
  const float* b1 = (const float*)d_in[3];
  const float* W2 = (const float*)d_in[4];
  const float* b2 = (const float*)d_in[5];
  float* out = (float*)d_out;

  char* ws = (char*)d_ws;
  size_t off = 0;
  auto alloc = [&](size_t bytes) {
    char* p = ws + off;
    off += (bytes + 255) & ~(size_t)255;
    return p;
  };

  unsigned int* deg_part = (unsigned int*)alloc((size_t)NPART * N * 4);
  float* dinv       = (float*)alloc((size_t)N * 4);
  float* s_part     = (float*)alloc((size_t)PCH * N * 4);
  float* z          = (float*)alloc((size_t)N * HID * 4);
  float* wz         = (float*)alloc((size_t)N * HID * 4);
  float* u_part     = (float*)alloc(256 * 16 * 4);
  unsigned int* done = (unsigned int*)alloc(256);
  float* t_part     = (float*)alloc((size_t)RCHUNK * N * HID * 4);
  unsigned long long* maskT = (unsigned long long*)alloc((size_t)N * NWORDS * 8);
  bool use_mask = (ws_size >= off);   // ~55 MB needed for the mask path

  if (use_mask) {
    k_mask_deg<<<dim3(NXB, RY), 512, 0, stream>>>(A, maskT, deg_part);
    k_dinvz<<<N / 64, 256, 0, stream>>>(deg_part, NPART, x, W1, dinv, z, wz, done);
    k_mid<<<1536, 256, 0, stream>>>(maskT, dinv, wz, s_part, t_part);
    k_combine<<<256, 64, 0, stream>>>(t_part, z, dinv, s_part, b1, W2, b2,
                                      u_part, done, out);
  } else {
    hipMemsetAsync(deg_part, 0, (size_t)N * 4, stream);
    k_deg_only<<<dim3(64, 32), 256, 0, stream>>>(A, deg_part);
    k_dinvz_fb<<<N / 64, 64, 0, stream>>>(deg_part, x, W1, dinv, z, wz);
    k_rowsum_direct<<<N / 4, 256, 0, stream>>>(A, dinv, s_part);
    k_spmm_direct<<<dim3(64, RCHUNK), 256, 0, stream>>>(A, wz, t_part);
    k_combine_fb<<<N / 64, 64, 0, stream>>>(t_part, z, dinv, s_part, b1, u_part);
    k_final_fb<<<1, 256, 0, stream>>>(u_part, W2, b2, out);
  }
}